// Round 8
// baseline (22.572 us; speedup 1.0000x reference)
//
#include <hip/hip_runtime.h>
#include <hip/hip_bf16.h>

// ---------------------------------------------------------------------------
// Round 8: two launches.
//   prep : builds B-side ONCE (vs per-wave-per-block in r7):
//          BH/BL = bf16 hi/lo fragments of C = [a, -2*mu*a], a = exp(-logvar),
//          FRAGMENT-ORDERED LANE-LINEAR: frag((cg,kk),lane) at
//          ((cg*8+kk)*64+lane)*16B  -> every main-loop B load is
//          global_load_dwordx4 at base + lane*16 (perfectly coalesced).
//          cvec[k] = sum_d mu^2*a.
//   main : A = [z^2,z] hi/lo staged lane-linear in LDS (r7 layout, zero
//          conflicts); loop = 2 B-loads + 4 ds_read_b128 + 6 MFMA + ~8 VALU.
// dist = Ah*Bh + Ah*Bl + Al*Bh (split-bf16, f32 acc);
// out = softmax_k(-0.5*dist) fused in epilogue (block owns all 256 k).
// MFMA 16x16x32 bf16 layouts [m89-verified]:
//   A: row=lane&15, k=(lane>>4)*8+j ; B: col=lane&15, same k ;
//   C/D: col=lane&15, row=(lane>>4)*4+reg.
// ---------------------------------------------------------------------------

typedef short     bf16x8  __attribute__((ext_vector_type(8)));
typedef float     f32x4   __attribute__((ext_vector_type(4)));
typedef unsigned short ushort_t;

constexpr int Bn = 8192, Kn = 256, Dn = 128;

// ws layout (ushort units): BH | BL | cvec(f32)
constexpr size_t BH_OFF = 0;
constexpr size_t BL_OFF = (size_t)16 * 8 * 64 * 8;   // 65536 ushorts = 128 KB
constexpr size_t CV_OFF = 2 * BL_OFF;                // 131072
constexpr size_t NEED_BYTES = CV_OFF * 2 + (size_t)Kn * 4;

__device__ __forceinline__ short bfbits(__hip_bfloat16 h) {
    return __builtin_bit_cast(short, h);
}

// 8 floats -> hi/lo bf16x8 via packed RNE converts (v_cvt_pk_bf16_f32)
__device__ __forceinline__ void split8(const float* f, bf16x8& hi, bf16x8& lo) {
    #pragma unroll
    for (int p = 0; p < 4; ++p) {
        const float2 fp = make_float2(f[2 * p], f[2 * p + 1]);
        const __hip_bfloat162 h2 = __float22bfloat162_rn(fp);
        hi[2 * p]     = bfbits(h2.x);
        hi[2 * p + 1] = bfbits(h2.y);
        const float2 rp = make_float2(fp.x - __bfloat162float(h2.x),
                                      fp.y - __bfloat162float(h2.y));
        const __hip_bfloat162 l2 = __float22bfloat162_rn(rp);
        lo[2 * p]     = bfbits(l2.x);
        lo[2 * p + 1] = bfbits(l2.y);
    }
}

// ---------------------------------------------------------------------------
// prep: 16 blocks (one per cg) x 512 thr. Thread = (kk = tid>>6, lane = tid&63)
// -> col = cg*16 + (lane&15), d0 = kk*16 + (lane>>4)*4.
// ---------------------------------------------------------------------------
__global__ __launch_bounds__(512)
void prep(const float* __restrict__ cent, const float* __restrict__ lvar,
          ushort_t* __restrict__ ws)
{
    __shared__ float red2[16][8];
    const int tid = threadIdx.x;
    const int kk  = tid >> 6;
    const int l   = tid & 63;
    const int lg  = l >> 4;
    const int ll  = l & 15;
    const int cg  = blockIdx.x;
    const int col = cg * 16 + ll;
    const int d0  = kk * 16 + lg * 4;

    const float4 cv = *reinterpret_cast<const float4*>(cent + (size_t)col * Dn + d0);
    const float4 l4 = *reinterpret_cast<const float4*>(lvar + (size_t)col * Dn + d0);
    const float a0 = __expf(-l4.x), a1 = __expf(-l4.y);
    const float a2 = __expf(-l4.z), a3 = __expf(-l4.w);
    const float f[8] = {a0, -2.0f * cv.x * a0, a1, -2.0f * cv.y * a1,
                        a2, -2.0f * cv.z * a2, a3, -2.0f * cv.w * a3};
    bf16x8 hi, lo;
    split8(f, hi, lo);
    const size_t off = ((size_t)(cg * 8 + kk) * 64 + l) * 8;
    *reinterpret_cast<bf16x8*>(ws + BH_OFF + off) = hi;
    *reinterpret_cast<bf16x8*>(ws + BL_OFF + off) = lo;

    // cvec partial: sum mu^2*a over this lane's 4 d's, reduce lg groups
    float cp = cv.x * cv.x * a0 + cv.y * cv.y * a1 +
               cv.z * cv.z * a2 + cv.w * cv.w * a3;
    cp += __shfl_xor(cp, 16);
    cp += __shfl_xor(cp, 32);
    if (lg == 0) red2[ll][kk] = cp;        // per (col, kk) sum
    __syncthreads();
    if (tid < 16) {
        float s = 0.f;
        #pragma unroll
        for (int q = 0; q < 8; ++q) s += red2[tid][q];
        reinterpret_cast<float*>(ws + CV_OFF)[cg * 16 + tid] = s;
    }
}

// ---------------------------------------------------------------------------
// main: 256 blocks x 1024 thr (16 waves, 4/SIMD). Block = 32 rows x 256 cols.
// Wave w owns cols [w*16, w*16+16). Loop: lean (loads+MFMA only).
// ---------------------------------------------------------------------------
__global__ __launch_bounds__(1024, 4)
void gmm_main(const float* __restrict__ z, const ushort_t* __restrict__ ws,
              float* __restrict__ out)
{
    __shared__ ushort_t Ah[2 * 8 * 64 * 8];   // 16 KB
    __shared__ ushort_t Al[2 * 8 * 64 * 8];   // 16 KB
    __shared__ float red[32][16];             // 2 KB

    const int tid = threadIdx.x;
    const int w   = tid >> 6;        // wave 0..15
    const int l   = tid & 63;
    const int lg  = l >> 4;
    const int ll  = l & 15;
    const int b0  = blockIdx.x * 32;
    const int n0  = w * 16;

    // ---- stage A = [z^2, z] hi/lo, lane-linear fragment order (r7) ----
    {
        const int r   = tid >> 9;
        const int kks = (tid >> 6) & 7;
        const int row = r * 16 + ll;
        const int d0  = kks * 16 + lg * 4;
        const float4 v = *reinterpret_cast<const float4*>(
            z + (size_t)(b0 + row) * Dn + d0);
        const float f[8] = {v.x * v.x, v.x, v.y * v.y, v.y,
                            v.z * v.z, v.z, v.w * v.w, v.w};
        bf16x8 hi, lo;
        split8(f, hi, lo);
        const int off = tid * 8;
        *reinterpret_cast<bf16x8*>(&Ah[off]) = hi;
        *reinterpret_cast<bf16x8*>(&Al[off]) = lo;
    }
    __syncthreads();

    const ushort_t* BH = ws + BH_OFF;
    const ushort_t* BL = ws + BL_OFF;
    const float*  cvec = reinterpret_cast<const float*>(ws + CV_OFF);

    f32x4 acc0 = (f32x4){0.f, 0.f, 0.f, 0.f};
    f32x4 acc1 = (f32x4){0.f, 0.f, 0.f, 0.f};

    // frag idx ((w*8+kk)*64+l)*8 = w*4096 + kk*512 + l*8  (ushort units)
    const size_t bbase = (size_t)w * 4096 + (size_t)l * 8;

    bf16x8 bh = *reinterpret_cast<const bf16x8*>(BH + bbase);
    bf16x8 bl = *reinterpret_cast<const bf16x8*>(BL + bbase);

    #pragma unroll
    for (int kk = 0; kk < 8; ++kk) {
        bf16x8 nbh, nbl;
        if (kk < 7) {   // prefetch next kk's B frags (L2-resident, lane-linear)
            nbh = *reinterpret_cast<const bf16x8*>(BH + bbase + (kk + 1) * 512);
            nbl = *reinterpret_cast<const bf16x8*>(BL + bbase + (kk + 1) * 512);
        }
        const int ao = kk * 512 + l * 8;     // lane-linear ds_read_b128
        const bf16x8 a0h = *reinterpret_cast<const bf16x8*>(&Ah[ao]);
        const bf16x8 a0l = *reinterpret_cast<const bf16x8*>(&Al[ao]);
        const bf16x8 a1h = *reinterpret_cast<const bf16x8*>(&Ah[4096 + ao]);
        const bf16x8 a1l = *reinterpret_cast<const bf16x8*>(&Al[4096 + ao]);

        acc0 = __builtin_amdgcn_mfma_f32_16x16x32_bf16(a0h, bh, acc0, 0, 0, 0);
        acc1 = __builtin_amdgcn_mfma_f32_16x16x32_bf16(a1h, bh, acc1, 0, 0, 0);
        acc0 = __builtin_amdgcn_mfma_f32_16x16x32_bf16(a0h, bl, acc0, 0, 0, 0);
        acc1 = __builtin_amdgcn_mfma_f32_16x16x32_bf16(a1h, bl, acc1, 0, 0, 0);
        acc0 = __builtin_amdgcn_mfma_f32_16x16x32_bf16(a0l, bh, acc0, 0, 0, 0);
        acc1 = __builtin_amdgcn_mfma_f32_16x16x32_bf16(a1l, bh, acc1, 0, 0, 0);

        bh = nbh; bl = nbl;
    }

    const float ck = cvec[n0 + ll];   // c[k] for this lane's col (C/D col = ll)

    // ---- epilogue: dist = acc + ck; softmax over k (16 waves x 16 cols) ----
    float dv[2][4];
    #pragma unroll
    for (int r = 0; r < 4; ++r) { dv[0][r] = acc0[r] + ck; dv[1][r] = acc1[r] + ck; }

    #pragma unroll
    for (int mi = 0; mi < 2; ++mi)
        #pragma unroll
        for (int r = 0; r < 4; ++r) {
            float t = dv[mi][r];
            t = fminf(t, __shfl_xor(t, 1));
            t = fminf(t, __shfl_xor(t, 2));
            t = fminf(t, __shfl_xor(t, 4));
            t = fminf(t, __shfl_xor(t, 8));
            if (ll == 0) red[mi * 16 + lg * 4 + r][w] = t;
        }
    __syncthreads();

    float gm[2][4];
    #pragma unroll
    for (int mi = 0; mi < 2; ++mi)
        #pragma unroll
        for (int r = 0; r < 4; ++r) {
            const int row = mi * 16 + lg * 4 + r;
            const f32x4* rp = reinterpret_cast<const f32x4*>(&red[row][0]);
            f32x4 m4 = rp[0];
            #pragma unroll
            for (int q = 1; q < 4; ++q) {
                f32x4 v = rp[q];
                m4[0] = fminf(m4[0], v[0]); m4[1] = fminf(m4[1], v[1]);
                m4[2] = fminf(m4[2], v[2]); m4[3] = fminf(m4[3], v[3]);
            }
            gm[mi][r] = fminf(fminf(m4[0], m4[1]), fminf(m4[2], m4[3]));
        }
    __syncthreads();   // all red reads done before reuse

    float pv[2][4];
    #pragma unroll
    for (int mi = 0; mi < 2; ++mi)
        #pragma unroll
        for (int r = 0; r < 4; ++r) {
            const float p = __expf(-0.5f * (dv[mi][r] - gm[mi][r]));
            pv[mi][r] = p;
            float s = p;
            s += __shfl_xor(s, 1);
            s += __shfl_xor(s, 2);
            s += __shfl_xor(s, 4);
            s += __shfl_xor(s, 8);
            if (ll == 0) red[mi * 16 + lg * 4 + r][w] = s;
        }
    __syncthreads();

    #pragma unroll
    for (int mi = 0; mi < 2; ++mi)
        #pragma unroll
        for (int r = 0; r < 4; ++r) {
            const int row = mi * 16 + lg * 4 + r;
            const f32x4* rp = reinterpret_cast<const f32x4*>(&red[row][0]);
            f32x4 s4 = rp[0];
            #pragma unroll
            for (int q = 1; q < 4; ++q) {
                f32x4 v = rp[q];
                s4[0] += v[0]; s4[1] += v[1]; s4[2] += v[2]; s4[3] += v[3];
            }
            const float inv = 1.0f / ((s4[0] + s4[1]) + (s4[2] + s4[3]));
            out[(size_t)(b0 + row) * Kn + n0 + ll] = pv[mi][r] * inv;
        }
}

// ---------------------------------------------------------------------------
// Fallback: round-7 fused kernel (known-good 21.9 us) if ws too small.
// ---------------------------------------------------------------------------
__global__ __launch_bounds__(1024, 4)
void gmm_fused(const float* __restrict__ z, const float* __restrict__ cent,
               const float* __restrict__ lvar, float* __restrict__ out)
{
    __shared__ ushort_t Ah[2 * 8 * 64 * 8];
    __shared__ ushort_t Al[2 * 8 * 64 * 8];
    __shared__ float red[32][16];

    const int tid = threadIdx.x;
    const int w   = tid >> 6;
    const int l   = tid & 63;
    const int lg  = l >> 4;
    const int ll  = l & 15;
    const int b0  = blockIdx.x * 32;
    const int n0  = w * 16;

    {
        const int r   = tid >> 9;
        const int kks = (tid >> 6) & 7;
        const int row = r * 16 + ll;
        const int d0  = kks * 16 + lg * 4;
        const float4 v = *reinterpret_cast<const float4*>(
            z + (size_t)(b0 + row) * Dn + d0);
        const float f[8] = {v.x * v.x, v.x, v.y * v.y, v.y,
                            v.z * v.z, v.z, v.w * v.w, v.w};
        bf16x8 hi, lo;
        split8(f, hi, lo);
        const int off = tid * 8;
        *reinterpret_cast<bf16x8*>(&Ah[off]) = hi;
        *reinterpret_cast<bf16x8*>(&Al[off]) = lo;
    }
    __syncthreads();

    f32x4 acc0 = (f32x4){0.f, 0.f, 0.f, 0.f};
    f32x4 acc1 = (f32x4){0.f, 0.f, 0.f, 0.f};
    float cpart = 0.0f;
    const size_t crow = (size_t)(n0 + ll) * Dn + lg * 4;

    float4 cv = *reinterpret_cast<const float4*>(cent + crow);
    float4 v4 = *reinterpret_cast<const float4*>(lvar + crow);

    #pragma unroll
    for (int kk = 0; kk < 8; ++kk) {
        float4 ncv, nv4;
        if (kk < 7) {
            ncv = *reinterpret_cast<const float4*>(cent + crow + (kk + 1) * 16);
            nv4 = *reinterpret_cast<const float4*>(lvar + crow + (kk + 1) * 16);
        }
        const float a0 = __expf(-v4.x), a1 = __expf(-v4.y);
        const float a2 = __expf(-v4.z), a3 = __expf(-v4.w);
        const float f[8] = {a0, -2.0f * cv.x * a0, a1, -2.0f * cv.y * a1,
                            a2, -2.0f * cv.z * a2, a3, -2.0f * cv.w * a3};
        bf16x8 Bh, Bl;
        split8(f, Bh, Bl);
        cpart += cv.x * cv.x * a0 + cv.y * cv.y * a1 +
                 cv.z * cv.z * a2 + cv.w * cv.w * a3;

        const int ao = kk * 512 + l * 8;
        const bf16x8 a0h = *reinterpret_cast<const bf16x8*>(&Ah[ao]);
        const bf16x8 a0l = *reinterpret_cast<const bf16x8*>(&Al[ao]);
        const bf16x8 a1h = *reinterpret_cast<const bf16x8*>(&Ah[4096 + ao]);
        const bf16x8 a1l = *reinterpret_cast<const bf16x8*>(&Al[4096 + ao]);

        acc0 = __builtin_amdgcn_mfma_f32_16x16x32_bf16(a0h, Bh, acc0, 0, 0, 0);
        acc1 = __builtin_amdgcn_mfma_f32_16x16x32_bf16(a1h, Bh, acc1, 0, 0, 0);
        acc0 = __builtin_amdgcn_mfma_f32_16x16x32_bf16(a0h, Bl, acc0, 0, 0, 0);
        acc1 = __builtin_amdgcn_mfma_f32_16x16x32_bf16(a1h, Bl, acc1, 0, 0, 0);
        acc0 = __builtin_amdgcn_mfma_f32_16x16x32_bf16(a0l, Bh, acc0, 0, 0, 0);
        acc1 = __builtin_amdgcn_mfma_f32_16x16x32_bf16(a1l, Bh, acc1, 0, 0, 0);

        cv = ncv; v4 = nv4;
    }
    cpart += __shfl_xor(cpart, 16);
    cpart += __shfl_xor(cpart, 32);
    const float ck = cpart;

    float dv[2][4];
    #pragma unroll
    for (int r = 0; r < 4; ++r) { dv[0][r] = acc0[r] + ck; dv[1][r] = acc1[r] + ck; }

    #pragma unroll
    for (int mi = 0; mi < 2; ++mi)
        #pragma unroll
        for (int r = 0; r < 4; ++r) {
            float t = dv[mi][r];
            t = fminf(t, __shfl_xor(t, 1));
            t = fminf(t, __shfl_xor(t, 2));
            t = fminf(t, __shfl_xor(t, 4));
            t = fminf(t, __shfl_xor(t, 8));
            if (ll == 0) red[mi * 16 + lg * 4 + r][w] = t;
        }
    __syncthreads();

    float gm[2][4];
    #pragma unroll
    for (int mi = 0; mi < 2; ++mi)
        #pragma unroll
        for (int r = 0; r < 4; ++r) {
            const int row = mi * 16 + lg * 4 + r;
            const f32x4* rp = reinterpret_cast<const f32x4*>(&red[row][0]);
            f32x4 m4 = rp[0];
            #pragma unroll
            for (int q = 1; q < 4; ++q) {
                f32x4 v = rp[q];
                m4[0] = fminf(m4[0], v[0]); m4[1] = fminf(m4[1], v[1]);
                m4[2] = fminf(m4[2], v[2]); m4[3] = fminf(m4[3], v[3]);
            }
            gm[mi][r] = fminf(fminf(m4[0], m4[1]), fminf(m4[2], m4[3]));
        }
    __syncthreads();

    float pv[2][4];
    #pragma unroll
    for (int mi = 0; mi < 2; ++mi)
        #pragma unroll
        for (int r = 0; r < 4; ++r) {
            const float p = __expf(-0.5f * (dv[mi][r] - gm[mi][r]));
            pv[mi][r] = p;
            float s = p;
            s += __shfl_xor(s, 1);
            s += __shfl_xor(s, 2);
            s += __shfl_xor(s, 4);
            s += __shfl_xor(s, 8);
            if (ll == 0) red[mi * 16 + lg * 4 + r][w] = s;
        }
    __syncthreads();

    #pragma unroll
    for (int mi = 0; mi < 2; ++mi)
        #pragma unroll
        for (int r = 0; r < 4; ++r) {
            const int row = mi * 16 + lg * 4 + r;
            const f32x4* rp = reinterpret_cast<const f32x4*>(&red[row][0]);
            f32x4 s4 = rp[0];
            #pragma unroll
            for (int q = 1; q < 4; ++q) {
                f32x4 v = rp[q];
                s4[0] += v[0]; s4[1] += v[1]; s4[2] += v[2]; s4[3] += v[3];
            }
            const float inv = 1.0f / ((s4[0] + s4[1]) + (s4[2] + s4[3]));
            out[(size_t)(b0 + row) * Kn + n0 + ll] = pv[mi][r] * inv;
        }
}

extern "C" void kernel_launch(void* const* d_in, const int* in_sizes, int n_in,
                              void* d_out, int out_size, void* d_ws, size_t ws_size,
                              hipStream_t stream) {
    const float* z      = (const float*)d_in[0];
    const float* cent   = (const float*)d_in[1];
    const float* logvar = (const float*)d_in[2];
    float* out = (float*)d_out;
    (void)in_sizes; (void)n_in; (void)out_size;

    if (ws_size >= NEED_BYTES) {
        ushort_t* ws = (ushort_t*)d_ws;
        hipLaunchKernelGGL(prep, dim3(16), dim3(512), 0, stream,
                           cent, logvar, ws);
        hipLaunchKernelGGL(gmm_main, dim3(Bn / 32), dim3(1024), 0, stream,
                           z, (const ushort_t*)ws, out);
    } else {
        hipLaunchKernelGGL(gmm_fused, dim3(Bn / 32), dim3(1024), 0, stream,
                           z, cent, logvar, out);
    }
}

// Round 10
// 20.870 us; speedup vs baseline: 1.0815x; 1.0815x over previous
//
#include <hip/hip_runtime.h>
#include <hip/hip_bf16.h>

// ---------------------------------------------------------------------------
// Round 9 (resubmit after infra failure): occupancy-first restructure.
//   prep (r8, unchanged): BH/BL = bf16 hi/lo fragments of C = [a, -2*mu*a],
//        a = exp(-logvar), fragment-ordered lane-linear; cvec[k] = sum mu^2*a.
//   main: 512 blocks x 1024 thr; wave = ONE 16x16 MFMA tile (16 rows x 16 k).
//        8192 waves total = 8 waves/SIMD, 2 blocks/CU (launch_bounds(1024,8),
//        ~45 live VGPR). Loop/kk: 2 global b128 (B) + 2 ds_read_b128 (A) +
//        3 MFMA. Hierarchical epilogue: wave-shuffle -> red[16][16] ->
//        wave 0 reduces -> LDS broadcast.
// dist = Ah*Bh + Ah*Bl + Al*Bh (split-bf16, f32 acc);
// out = softmax_k(-0.5*dist) fused (block owns all 256 k).
// MFMA 16x16x32 bf16 layouts [m89-verified]:
//   A: row=lane&15, k=(lane>>4)*8+j ; B: col=lane&15, same k ;
//   C/D: col=lane&15, row=(lane>>4)*4+reg.
// ---------------------------------------------------------------------------

typedef short     bf16x8  __attribute__((ext_vector_type(8)));
typedef float     f32x4   __attribute__((ext_vector_type(4)));
typedef unsigned short ushort_t;

constexpr int Bn = 8192, Kn = 256, Dn = 128;

// ws layout (ushort units): BH | BL | cvec(f32)
constexpr size_t BH_OFF = 0;
constexpr size_t BL_OFF = (size_t)16 * 8 * 64 * 8;   // 65536 ushorts = 128 KB
constexpr size_t CV_OFF = 2 * BL_OFF;                // 131072
constexpr size_t NEED_BYTES = CV_OFF * 2 + (size_t)Kn * 4;

__device__ __forceinline__ short bfbits(__hip_bfloat16 h) {
    return __builtin_bit_cast(short, h);
}

// 8 floats -> hi/lo bf16x8 via packed RNE converts (v_cvt_pk_bf16_f32)
__device__ __forceinline__ void split8(const float* f, bf16x8& hi, bf16x8& lo) {
    #pragma unroll
    for (int p = 0; p < 4; ++p) {
        const float2 fp = make_float2(f[2 * p], f[2 * p + 1]);
        const __hip_bfloat162 h2 = __float22bfloat162_rn(fp);
        hi[2 * p]     = bfbits(h2.x);
        hi[2 * p + 1] = bfbits(h2.y);
        const float2 rp = make_float2(fp.x - __bfloat162float(h2.x),
                                      fp.y - __bfloat162float(h2.y));
        const __hip_bfloat162 l2 = __float22bfloat162_rn(rp);
        lo[2 * p]     = bfbits(l2.x);
        lo[2 * p + 1] = bfbits(l2.y);
    }
}

// ---------------------------------------------------------------------------
// prep: 16 blocks (one per 16-col group cg) x 512 thr (r8, proven).
// ---------------------------------------------------------------------------
__global__ __launch_bounds__(512)
void prep(const float* __restrict__ cent, const float* __restrict__ lvar,
          ushort_t* __restrict__ ws)
{
    __shared__ float red2[16][8];
    const int tid = threadIdx.x;
    const int kk  = tid >> 6;
    const int l   = tid & 63;
    const int lg  = l >> 4;
    const int ll  = l & 15;
    const int cg  = blockIdx.x;
    const int col = cg * 16 + ll;
    const int d0  = kk * 16 + lg * 4;

    const float4 cv = *reinterpret_cast<const float4*>(cent + (size_t)col * Dn + d0);
    const float4 l4 = *reinterpret_cast<const float4*>(lvar + (size_t)col * Dn + d0);
    const float a0 = __expf(-l4.x), a1 = __expf(-l4.y);
    const float a2 = __expf(-l4.z), a3 = __expf(-l4.w);
    const float f[8] = {a0, -2.0f * cv.x * a0, a1, -2.0f * cv.y * a1,
                        a2, -2.0f * cv.z * a2, a3, -2.0f * cv.w * a3};
    bf16x8 hi, lo;
    split8(f, hi, lo);
    const size_t off = ((size_t)(cg * 8 + kk) * 64 + l) * 8;
    *reinterpret_cast<bf16x8*>(ws + BH_OFF + off) = hi;
    *reinterpret_cast<bf16x8*>(ws + BL_OFF + off) = lo;

    float cp = cv.x * cv.x * a0 + cv.y * cv.y * a1 +
               cv.z * cv.z * a2 + cv.w * cv.w * a3;
    cp += __shfl_xor(cp, 16);
    cp += __shfl_xor(cp, 32);
    if (lg == 0) red2[ll][kk] = cp;
    __syncthreads();
    if (tid < 16) {
        float s = 0.f;
        #pragma unroll
        for (int q = 0; q < 8; ++q) s += red2[tid][q];
        reinterpret_cast<float*>(ws + CV_OFF)[cg * 16 + tid] = s;
    }
}

// ---------------------------------------------------------------------------
// main: 512 blocks x 1024 thr (16 waves). Block = 16 b-rows x all 256 cols.
// Wave w = one 16x16 tile: rows b0..b0+15, cols w*16..w*16+15.
// ---------------------------------------------------------------------------
__global__ __launch_bounds__(1024, 8)
void gmm_main(const float* __restrict__ z, const ushort_t* __restrict__ ws,
              float* __restrict__ out)
{
    __shared__ ushort_t Ah[8 * 64 * 8];   // 8 KB  (16 rows x 256 feats, hi)
    __shared__ ushort_t Al[8 * 64 * 8];   // 8 KB  (lo)
    __shared__ float red[16][16];         // 1 KB  [row][wave] partials
    __shared__ float gsc[2][16];          // [0]=row min, [1]=row 1/sum

    const int tid = threadIdx.x;
    const int w   = tid >> 6;        // wave 0..15 -> col group
    const int l   = tid & 63;
    const int lg  = l >> 4;          // 0..3
    const int ll  = l & 15;
    const int b0  = blockIdx.x * 16;
    const int n0  = w * 16;

    // ---- stage A = [z^2, z] hi/lo, lane-linear fragment order (512 thr) ----
    // thread t<512 -> (kks = t>>6, lane = t&63): frag slot holds
    // F[row = lane&15][k = kks*32 + (lane>>4)*8 + j], i.e. z[row][d0..d0+3],
    // d0 = kks*16 + (lane>>4)*4.
    if (tid < 512) {
        const int kks = tid >> 6;
        const int d0  = kks * 16 + lg * 4;
        const float4 v = *reinterpret_cast<const float4*>(
            z + (size_t)(b0 + ll) * Dn + d0);
        const float f[8] = {v.x * v.x, v.x, v.y * v.y, v.y,
                            v.z * v.z, v.z, v.w * v.w, v.w};
        bf16x8 hi, lo;
        split8(f, hi, lo);
        const int off = tid * 8;     // == (kks*64 + lane)*8 (lane-linear)
        *reinterpret_cast<bf16x8*>(&Ah[off]) = hi;
        *reinterpret_cast<bf16x8*>(&Al[off]) = lo;
    }
    __syncthreads();

    const ushort_t* BH = ws + BH_OFF;
    const ushort_t* BL = ws + BL_OFF;
    const float*  cvec = reinterpret_cast<const float*>(ws + CV_OFF);

    // ---- loop: per kk, 2 global b128 (B) + 2 ds_read_b128 (A) + 3 MFMA ----
    f32x4 acc = (f32x4){0.f, 0.f, 0.f, 0.f};
    const size_t bbase = ((size_t)w * 8 * 64 + l) * 8;   // ((w*8+kk)*64+l)*8

    #pragma unroll
    for (int kk = 0; kk < 8; ++kk) {
        const bf16x8 bh = *reinterpret_cast<const bf16x8*>(BH + bbase + kk * 512);
        const bf16x8 bl = *reinterpret_cast<const bf16x8*>(BL + bbase + kk * 512);
        const int ao = kk * 512 + l * 8;
        const bf16x8 ah = *reinterpret_cast<const bf16x8*>(&Ah[ao]);
        const bf16x8 al = *reinterpret_cast<const bf16x8*>(&Al[ao]);

        acc = __builtin_amdgcn_mfma_f32_16x16x32_bf16(ah, bh, acc, 0, 0, 0);
        acc = __builtin_amdgcn_mfma_f32_16x16x32_bf16(ah, bl, acc, 0, 0, 0);
        acc = __builtin_amdgcn_mfma_f32_16x16x32_bf16(al, bh, acc, 0, 0, 0);
    }

    // ---- epilogue ----
    const float ck = cvec[n0 + ll];     // c[col], C/D col = ll
    float dv[4], pv[4];
    #pragma unroll
    for (int r = 0; r < 4; ++r) dv[r] = acc[r] + ck;

    // per-wave col-min for each of this lane-group's rows (row = lg*4+r)
    #pragma unroll
    for (int r = 0; r < 4; ++r) {
        float t = dv[r];
        t = fminf(t, __shfl_xor(t, 1));
        t = fminf(t, __shfl_xor(t, 2));
        t = fminf(t, __shfl_xor(t, 4));
        t = fminf(t, __shfl_xor(t, 8));
        if (ll == 0) red[lg * 4 + r][w] = t;
    }
    __syncthreads();

    // wave 0: reduce 16 partials per row -> gsc[0][row]
    if (w == 0) {
        const int row = l >> 2, q = l & 3;
        const f32x4 v = *reinterpret_cast<const f32x4*>(&red[row][q * 4]);
        float m = fminf(fminf(v[0], v[1]), fminf(v[2], v[3]));
        m = fminf(m, __shfl_xor(m, 1));
        m = fminf(m, __shfl_xor(m, 2));
        if (q == 0) gsc[0][row] = m;
    }
    __syncthreads();

    #pragma unroll
    for (int r = 0; r < 4; ++r) {
        pv[r] = __expf(-0.5f * (dv[r] - gsc[0][lg * 4 + r]));
        float s = pv[r];
        s += __shfl_xor(s, 1);
        s += __shfl_xor(s, 2);
        s += __shfl_xor(s, 4);
        s += __shfl_xor(s, 8);
        if (ll == 0) red[lg * 4 + r][w] = s;
    }
    __syncthreads();

    // wave 0: sum 16 partials per row -> gsc[1][row] = 1/sum
    if (w == 0) {
        const int row = l >> 2, q = l & 3;
        const f32x4 v = *reinterpret_cast<const f32x4*>(&red[row][q * 4]);
        float s = (v[0] + v[1]) + (v[2] + v[3]);
        s += __shfl_xor(s, 1);
        s += __shfl_xor(s, 2);
        if (q == 0) gsc[1][row] = 1.0f / s;
    }
    __syncthreads();

    #pragma unroll
    for (int r = 0; r < 4; ++r) {
        const int row = lg * 4 + r;
        out[(size_t)(b0 + row) * Kn + n0 + ll] = pv[r] * gsc[1][row];
    }
}

// ---------------------------------------------------------------------------
// Fallback: round-7 fused kernel (known-good 21.9 us) if ws too small.
// ---------------------------------------------------------------------------
__global__ __launch_bounds__(1024, 4)
void gmm_fused(const float* __restrict__ z, const float* __restrict__ cent,
               const float* __restrict__ lvar, float* __restrict__ out)
{
    __shared__ ushort_t Ah[2 * 8 * 64 * 8];
    __shared__ ushort_t Al[2 * 8 * 64 * 8];
    __shared__ float red[32][16];

    const int tid = threadIdx.x;
    const int w   = tid >> 6;
    const int l   = tid & 63;
    const int lg  = l >> 4;
    const int ll  = l & 15;
    const int b0  = blockIdx.x * 32;
    const int n0  = w * 16;

    {
        const int r   = tid >> 9;
        const int kks = (tid >> 6) & 7;
        const int row = r * 16 + ll;
        const int d0  = kks * 16 + lg * 4;
        const float4 v = *reinterpret_cast<const float4*>(
            z + (size_t)(b0 + row) * Dn + d0);
        const float f[8] = {v.x * v.x, v.x, v.y * v.y, v.y,
                            v.z * v.z, v.z, v.w * v.w, v.w};
        bf16x8 hi, lo;
        split8(f, hi, lo);
        const int off = tid * 8;
        *reinterpret_cast<bf16x8*>(&Ah[off]) = hi;
        *reinterpret_cast<bf16x8*>(&Al[off]) = lo;
    }
    __syncthreads();

    f32x4 acc0 = (f32x4){0.f, 0.f, 0.f, 0.f};
    f32x4 acc1 = (f32x4){0.f, 0.f, 0.f, 0.f};
    float cpart = 0.0f;
    const size_t crow = (size_t)(n0 + ll) * Dn + lg * 4;

    float4 cv = *reinterpret_cast<const float4*>(cent + crow);
    float4 v4 = *reinterpret_cast<const float4*>(lvar + crow);

    #pragma unroll
    for (int kk = 0; kk < 8; ++kk) {
        float4 ncv, nv4;
        if (kk < 7) {
            ncv = *reinterpret_cast<const float4*>(cent + crow + (kk + 1) * 16);
            nv4 = *reinterpret_cast<const float4*>(lvar + crow + (kk + 1) * 16);
        }
        const float a0 = __expf(-v4.x), a1 = __expf(-v4.y);
        const float a2 = __expf(-v4.z), a3 = __expf(-v4.w);
        const float f[8] = {a0, -2.0f * cv.x * a0, a1, -2.0f * cv.y * a1,
                            a2, -2.0f * cv.z * a2, a3, -2.0f * cv.w * a3};
        bf16x8 Bh, Bl;
        split8(f, Bh, Bl);
        cpart += cv.x * cv.x * a0 + cv.y * cv.y * a1 +
                 cv.z * cv.z * a2 + cv.w * cv.w * a3;

        const int ao = kk * 512 + l * 8;
        const bf16x8 a0h = *reinterpret_cast<const bf16x8*>(&Ah[ao]);
        const bf16x8 a0l = *reinterpret_cast<const bf16x8*>(&Al[ao]);
        const bf16x8 a1h = *reinterpret_cast<const bf16x8*>(&Ah[4096 + ao]);
        const bf16x8 a1l = *reinterpret_cast<const bf16x8*>(&Al[4096 + ao]);

        acc0 = __builtin_amdgcn_mfma_f32_16x16x32_bf16(a0h, Bh, acc0, 0, 0, 0);
        acc1 = __builtin_amdgcn_mfma_f32_16x16x32_bf16(a1h, Bh, acc1, 0, 0, 0);
        acc0 = __builtin_amdgcn_mfma_f32_16x16x32_bf16(a0h, Bl, acc0, 0, 0, 0);
        acc1 = __builtin_amdgcn_mfma_f32_16x16x32_bf16(a1h, Bl, acc1, 0, 0, 0);
        acc0 = __builtin_amdgcn_mfma_f32_16x16x32_bf16(a0l, Bh, acc0, 0, 0, 0);
        acc1 = __builtin_amdgcn_mfma_f32_16x16x32_bf16(a1l, Bh, acc1, 0, 0, 0);

        cv = ncv; v4 = nv4;
    }
    cpart += __shfl_xor(cpart, 16);
    cpart += __shfl_xor(cpart, 32);
    const float ck = cpart;

    float dv[2][4];
    #pragma unroll
    for (int r = 0; r < 4; ++r) { dv[0][r] = acc0[r] + ck; dv[1][r] = acc1[r] + ck; }

    #pragma unroll
    for (int mi = 0; mi < 2; ++mi)
        #pragma unroll
        for (int r = 0; r < 4; ++r) {
            float t = dv[mi][r];
            t = fminf(t, __shfl_xor(t, 1));
            t = fminf(t, __shfl_xor(t, 2));
            t = fminf(t, __shfl_xor(t, 4));
            t = fminf(t, __shfl_xor(t, 8));
            if (ll == 0) red[mi * 16 + lg * 4 + r][w] = t;
        }
    __syncthreads();

    float gm[2][4];
    #pragma unroll
    for (int mi = 0; mi < 2; ++mi)
        #pragma unroll
        for (int r = 0; r < 4; ++r) {
            const int row = mi * 16 + lg * 4 + r;
            const f32x4* rp = reinterpret_cast<const f32x4*>(&red[row][0]);
            f32x4 m4 = rp[0];
            #pragma unroll
            for (int q = 1; q < 4; ++q) {
                f32x4 v = rp[q];
                m4[0] = fminf(m4[0], v[0]); m4[1] = fminf(m4[1], v[1]);
                m4[2] = fminf(m4[2], v[2]); m4[3] = fminf(m4[3], v[3]);
            }
            gm[mi][r] = fminf(fminf(m4[0], m4[1]), fminf(m4[2], m4[3]));
        }
    __syncthreads();

    float pv[2][4];
    #pragma unroll
    for (int mi = 0; mi < 2; ++mi)
        #pragma unroll
        for (int r = 0; r < 4; ++r) {
            const float p = __expf(-0.5f * (dv[mi][r] - gm[mi][r]));
            pv[mi][r] = p;
            float s = p;
            s += __shfl_xor(s, 1);
            s += __shfl_xor(s, 2);
            s += __shfl_xor(s, 4);
            s += __shfl_xor(s, 8);
            if (ll == 0) red[mi * 16 + lg * 4 + r][w] = s;
        }
    __syncthreads();

    #pragma unroll
    for (int mi = 0; mi < 2; ++mi)
        #pragma unroll
        for (int r = 0; r < 4; ++r) {
            const int row = mi * 16 + lg * 4 + r;
            const f32x4* rp = reinterpret_cast<const f32x4*>(&red[row][0]);
            f32x4 s4 = rp[0];
            #pragma unroll
            for (int q = 1; q < 4; ++q) {
                f32x4 v = rp[q];
                s4[0] += v[0]; s4[1] += v[1]; s4[2] += v[2]; s4[3] += v[3];
            }
            const float inv = 1.0f / ((s4[0] + s4[1]) + (s4[2] + s4[3]));
            out[(size_t)(b0 + row) * Kn + n0 + ll] = pv[mi][r] * inv;
        }
}

extern "C" void kernel_launch(void* const* d_in, const int* in_sizes, int n_in,
                              void* d_out, int out_size, void* d_ws, size_t ws_size,
                              hipStream_t stream) {
    const float* z      = (const float*)d_in[0];
    const float* cent   = (const float*)d_in[1];
    const float* logvar = (const float*)d_in[2];
    float* out = (float*)d_out;
    (void)in_sizes; (void)n_in; (void)out_size;

    if (ws_size >= NEED_BYTES) {
        ushort_t* ws = (ushort_t*)d_ws;
        hipLaunchKernelGGL(prep, dim3(16), dim3(512), 0, stream,
                           cent, logvar, ws);
        hipLaunchKernelGGL(gmm_main, dim3(Bn / 16), dim3(1024), 0, stream,
                           z, (const ushort_t*)ws, out);
    } else {
        hipLaunchKernelGGL(gmm_fused, dim3(Bn / 32), dim3(1024), 0, stream,
                           z, cent, logvar, out);
    }
}